// Round 10
// baseline (304.974 us; speedup 1.0000x reference)
//
#include <hip/hip_runtime.h>
#include <hip/hip_bf16.h>

#define NH 16
#define HD 64
#define SEQ 2048
#define HID 1024
#define MAXP 2048
#define ST_R 68   // u16 stride of transposed R tiles (mult of 4 for b64 writes)

typedef float f32x4 __attribute__((ext_vector_type(4)));
typedef short bf16x8 __attribute__((ext_vector_type(8)));
typedef unsigned short u16;
typedef unsigned short u16x8 __attribute__((ext_vector_type(8)));

// Scalar HW convert; compiler fuses adjacent pairs into v_cvt_pk_bf16_f32 (m240).
__device__ __forceinline__ u16 f2bf_hw(float x) {
  union { __hip_bfloat16 h; u16 u; } v;
  v.h = __float2bfloat16(x);
  return v.u;
}
__device__ __forceinline__ unsigned pk2(float a, float b) {
  return (unsigned)f2bf_hw(a) | ((unsigned)f2bf_hw(b) << 16);
}
__device__ __forceinline__ float bf2f(u16 h) {
  union { unsigned u; float f; } v; v.u = ((unsigned)h) << 16;
  return v.f;
}

// XOR-swizzle for bf16 tiles with 64-elem (128B) row stride.
#define SWZ(r, c) ((r) * 64 + ((((c) >> 3) ^ ((r) & 7)) << 3) + ((c) & 7))

// async global->LDS 16B: LDS dest = wave-uniform base + lane*16; global src per-lane.
__device__ __forceinline__ void async_copy16(void* lds, const void* g) {
  __builtin_amdgcn_global_load_lds(
      (const __attribute__((address_space(1))) unsigned int*)g,
      (__attribute__((address_space(3))) unsigned int*)lds, 16, 0, 0);
}
__device__ __forceinline__ void vwait0() { asm volatile("s_waitcnt vmcnt(0)" ::: "memory"); }
__device__ __forceinline__ void lwait0() { asm volatile("s_waitcnt lgkmcnt(0)" ::: "memory"); }

// ---------------- fp32 -> bf16 bulk convert ----------------
__global__ __launch_bounds__(256) void cvt_f32_bf16(
    const float* __restrict__ src, u16* __restrict__ dst, int n4) {
  int i = blockIdx.x * 256 + threadIdx.x;
  const int stride = gridDim.x * 256;
  for (; i < n4; i += stride) {
    const float4 v = reinterpret_cast<const float4*>(src)[i];
    uint2 d;
    d.x = pk2(v.x, v.y);
    d.y = pk2(v.z, v.w);
    reinterpret_cast<uint2*>(dst)[i] = d;
  }
}

// ---------------- Fused Q/K/V projection: O = bf16((X @ W^T + b) * scale) ----
// Q (wsel==0) pre-scaled by 0.125*log2(e): folds 1/sqrt(64) AND the exp->exp2
// conversion into Q (inherited by both Q.K and Q.E terms).
__global__ __launch_bounds__(256) void proj_mfma(
    const u16* __restrict__ Xb, const u16* __restrict__ W0,
    const u16* __restrict__ W1, const u16* __restrict__ W2,
    const float* __restrict__ b0, const float* __restrict__ b1,
    const float* __restrict__ b2,
    u16* __restrict__ O0, u16* __restrict__ O1, u16* __restrict__ O2) {
  __shared__ u16 sA[128 * 64];
  __shared__ u16 sB[128 * 64];
  const int t = threadIdx.x, lane = t & 63, w = t >> 6;
  const int g = lane >> 4, li = lane & 15;
  const int wsel = blockIdx.x >> 3;
  const int n0 = (blockIdx.x & 7) * 128, m0 = blockIdx.y * 128;
  const u16* Wb = wsel == 0 ? W0 : (wsel == 1 ? W1 : W2);
  const float* bias = wsel == 0 ? b0 : (wsel == 1 ? b1 : b2);
  u16* Ob = wsel == 0 ? O0 : (wsel == 1 ? O1 : O2);
  const float oscale = wsel == 0 ? 0.125f * 1.44269504f : 1.0f;
  const int wr = w >> 1, wc = w & 1;

  f32x4 acc[4][4];
#pragma unroll
  for (int i = 0; i < 4; ++i)
#pragma unroll
    for (int j = 0; j < 4; ++j) acc[i][j] = (f32x4)0.0f;

  for (int k0 = 0; k0 < HID; k0 += 64) {
    __syncthreads();
#pragma unroll
    for (int i = 0; i < 4; ++i) {
      const int idx = (w * 4 + i) * 64 + lane;
      const int row = idx >> 3, sch = (idx & 7) ^ (row & 7);
      async_copy16(&sA[(w * 4 + i) * 512], Xb + (size_t)(m0 + row) * HID + k0 + sch * 8);
      async_copy16(&sB[(w * 4 + i) * 512], Wb + (size_t)(n0 + row) * HID + k0 + sch * 8);
    }
    __syncthreads();
    bf16x8 af[4][2], bfr[4][2];
#pragma unroll
    for (int i = 0; i < 4; ++i)
#pragma unroll
      for (int c = 0; c < 2; ++c)
        af[i][c] = *reinterpret_cast<const bf16x8*>(&sA[SWZ(wr * 64 + 16 * i + li, 32 * c + 8 * g)]);
#pragma unroll
    for (int j = 0; j < 4; ++j)
#pragma unroll
      for (int c = 0; c < 2; ++c)
        bfr[j][c] = *reinterpret_cast<const bf16x8*>(&sB[SWZ(wc * 64 + 16 * j + li, 32 * c + 8 * g)]);
#pragma unroll
    for (int i = 0; i < 4; ++i)
#pragma unroll
      for (int j = 0; j < 4; ++j)
#pragma unroll
        for (int c = 0; c < 2; ++c)
          acc[i][j] = __builtin_amdgcn_mfma_f32_16x16x32_bf16(af[i][c], bfr[j][c], acc[i][j], 0, 0, 0);
  }

#pragma unroll
  for (int j = 0; j < 4; ++j) {
    const float bj = bias[n0 + wc * 64 + 16 * j + li];
#pragma unroll
    for (int i = 0; i < 4; ++i)
#pragma unroll
      for (int r = 0; r < 4; ++r)
        Ob[(size_t)(m0 + wr * 64 + 16 * i + 4 * g + r) * HID + n0 + wc * 64 + 16 * j + li] =
            f2bf_hw((acc[i][j][r] + bj) * oscale);
  }
}

// ---------------- V transpose: Vt[b][h][d][s] <- V[b][s][h*64+d] ----------------
__global__ __launch_bounds__(256) void transpose_v(
    const u16* __restrict__ Vin, u16* __restrict__ Vt) {
  __shared__ u16 tile[64 * 65];
  const int t = threadIdx.x;
  const int s0 = blockIdx.x * 64, h = blockIdx.y, b = blockIdx.z;
  const int r = t >> 2, c0 = (t & 3) * 16;
  const u16* gp = Vin + (size_t)(b * SEQ + s0 + r) * HID + h * HD + c0;
  const u16x8 a0 = *reinterpret_cast<const u16x8*>(gp);
  const u16x8 a1 = *reinterpret_cast<const u16x8*>(gp + 8);
#pragma unroll
  for (int i = 0; i < 8; ++i) { tile[r * 65 + c0 + i] = a0[i]; tile[r * 65 + c0 + 8 + i] = a1[i]; }
  __syncthreads();
  const int d = t >> 2, sc = (t & 3) * 16;
  u16x8 o0, o1;
#pragma unroll
  for (int i = 0; i < 8; ++i) {
    o0[i] = tile[(sc + i) * 65 + d];
    o1[i] = tile[(sc + 8 + i) * 65 + d];
  }
  u16* op = Vt + ((size_t)(b * NH + h) * HD + d) * SEQ + s0 + sc;
  *reinterpret_cast<u16x8*>(op) = o0;
  *reinterpret_cast<u16x8*>(op + 8) = o1;
}

// ---------------- Fused MFMA attention v6b ----------------
// R8's 2-barrier pipeline + exp2-folded softmax + row-sum via ones-column MFMA
// (accX) + V fragments loaded global->reg at bar#1 (consumed at PV ~1000cyc
// later). bf16 packing via scalar __float2bfloat16 (compiler fuses to cvt_pk).
__global__ __launch_bounds__(256, 2) void attn_mfma6(
    const u16* __restrict__ Q, const u16* __restrict__ K,
    const u16* __restrict__ Vt, const u16* __restrict__ E,
    float* __restrict__ out) {
  __shared__ u16 sK0[64 * 64];     // K buffers; current one becomes P after #2
  __shared__ u16 sK1[64 * 64];
  __shared__ u16 sE[128 * 64];
  __shared__ u16 sRq[128 * ST_R];  // [j][qi] transposed
  __shared__ u16 sRk[128 * ST_R];  // [j][ki]

  const int t = threadIdx.x;
  const int lane = t & 63, w = t >> 6;
  const int g = lane >> 4, li = lane & 15;
  const int q0 = blockIdx.x * 64;
  const int h = blockIdx.y, b = blockIdx.z;
  const size_t qkbase = (size_t)b * SEQ * HID + (size_t)h * HD;
  const size_t vtbase = (size_t)(b * NH + h) * HD * SEQ;

  bf16x8 qA[2];
#pragma unroll
  for (int c = 0; c < 2; ++c)
    qA[c] = *reinterpret_cast<const bf16x8*>(
        Q + qkbase + (size_t)(q0 + 16 * w + li) * HID + 32 * c + 8 * g);

  bf16x8 ones;
#pragma unroll
  for (int i = 0; i < 8; ++i) ones[i] = (short)0x3F80;  // bf16 1.0

  f32x4 accO[4];
  f32x4 accX = (f32x4)0.0f;   // row-sum of P (denominator), via ones-MFMA
#pragma unroll
  for (int n = 0; n < 4; ++n) accO[n] = (f32x4)0.0f;

  // k0-invariant gather/write bases; j = 63+qi-ki, biased so unrolled offsets
  // are non-negative compile-time constants.
  const int jb48 = 15 + 16 * w + 4 * g - li;             // in [0, 75]
  const u16* gqp = &sRq[jb48 * ST_R + 16 * w + 4 * g];   // + (48+r-16n)*ST_R + r
  const u16* gkp = &sRk[jb48 * ST_R + li];               // + (48+r-16n)*ST_R + 16n
  u16* rkw = &sRk[li * ST_R + 16 * w + 4 * g];           // + m*16*ST_R
  u16* rqw = &sRq[li * ST_R + 16 * w + 4 * g];

  const int sidx2 = w * 2 * 64 + lane;
  const int sidx4 = w * 4 * 64 + lane;

  // ---- prologue: stage K(0), E(0); drain ----
  {
    const int eb0 = 1984 + q0;
#pragma unroll
    for (int i = 0; i < 2; ++i) {
      const int idx = sidx2 + i * 64;
      const int row = idx >> 3, sch = (idx & 7) ^ (row & 7);
      async_copy16(&sK0[(w * 2 + i) * 512], K + qkbase + (size_t)row * HID + sch * 8);
    }
#pragma unroll
    for (int i = 0; i < 4; ++i) {
      const int idx = sidx4 + i * 64;
      const int row = idx >> 3, sch = (idx & 7) ^ (row & 7);
      const int er = min(max(eb0 + row, 0), 2 * MAXP - 2);
      async_copy16(&sE[(w * 4 + i) * 512], E + (size_t)er * HD + sch * 8);
    }
    vwait0();
  }

  for (int k0 = 0; k0 < SEQ; k0 += 64) {
    const int p = (k0 >> 6) & 1;
    u16* kcur = p ? sK1 : sK0;
    u16* knxt = p ? sK0 : sK1;

    __builtin_amdgcn_s_barrier();   // #1: K(t),E(t) visible; knxt reusable
    // ---- issue K(t+1) staging; load V(t) fragments global->reg ----
#pragma unroll
    for (int i = 0; i < 2; ++i) {
      const int idx = sidx2 + i * 64;
      const int row = idx >> 3, sch = (idx & 7) ^ (row & 7);
      async_copy16(&knxt[(w * 2 + i) * 512], K + qkbase + (size_t)(k0 + 64 + row) * HID + sch * 8);
    }
    bf16x8 vf[4][2];
#pragma unroll
    for (int n = 0; n < 4; ++n)
#pragma unroll
      for (int c = 0; c < 2; ++c)
        vf[n][c] = *reinterpret_cast<const bf16x8*>(
            Vt + vtbase + (size_t)(16 * n + li) * SEQ + k0 + 32 * c + 8 * g);

    // ---- S = Q'.K^T ----
    bf16x8 kA[2];
#pragma unroll
    for (int c = 0; c < 2; ++c)
      kA[c] = *reinterpret_cast<const bf16x8*>(&kcur[SWZ(16 * w + li, 32 * c + 8 * g)]);
    f32x4 aqk[4];
#pragma unroll
    for (int n = 0; n < 4; ++n) {
      aqk[n] = (f32x4)0.0f;
#pragma unroll
      for (int c = 0; c < 2; ++c) {
        const bf16x8 kB = *reinterpret_cast<const bf16x8*>(&kcur[SWZ(16 * n + li, 32 * c + 8 * g)]);
        aqk[n] = __builtin_amdgcn_mfma_f32_16x16x32_bf16(qA[c], kB, aqk[n], 0, 0, 0);
      }
    }
    // ---- Rq = Q'.E^T, Rk = K.E^T; packed b64 writes, transposed [j][col] ----
    __builtin_amdgcn_s_setprio(1);
#pragma unroll
    for (int m = 0; m < 8; ++m) {
      bf16x8 eB[2];
#pragma unroll
      for (int c = 0; c < 2; ++c)
        eB[c] = *reinterpret_cast<const bf16x8*>(&sE[SWZ(16 * m + li, 32 * c + 8 * g)]);
      f32x4 ak = (f32x4)0.0f, aq = (f32x4)0.0f;
#pragma unroll
      for (int c = 0; c < 2; ++c) {
        ak = __builtin_amdgcn_mfma_f32_16x16x32_bf16(kA[c], eB[c], ak, 0, 0, 0);
        aq = __builtin_amdgcn_mfma_f32_16x16x32_bf16(qA[c], eB[c], aq, 0, 0, 0);
      }
      uint2 dk, dq;
      dk.x = pk2(ak[0], ak[1]); dk.y = pk2(ak[2], ak[3]);
      dq.x = pk2(aq[0], aq[1]); dq.y = pk2(aq[2], aq[3]);
      *reinterpret_cast<uint2*>(rkw + m * 16 * ST_R) = dk;
      *reinterpret_cast<uint2*>(rqw + m * 16 * ST_R) = dq;
    }
    __builtin_amdgcn_s_setprio(0);

    vwait0();                       // K(t+1), vf(t) landed (in flight since top)
    lwait0();                       // R-writes retired
    __builtin_amdgcn_s_barrier();   // #2: sRk/sRq + K(t+1) visible to all

    // ---- issue E(t+1) (all sE reads happened before #2) ----
    {
      const int ebn = 1920 + q0 - k0;  // eb(t+1)
#pragma unroll
      for (int i = 0; i < 4; ++i) {
        const int idx = sidx4 + i * 64;
        const int row = idx >> 3, sch = (idx & 7) ^ (row & 7);
        const int er = min(max(ebn + row, 0), 2 * MAXP - 2);
        async_copy16(&sE[(w * 4 + i) * 512], E + (size_t)er * HD + sch * 8);
      }
    }

    // ---- scores: gather + exp2 + P write (into kcur, dead K tile) ----
#pragma unroll
    for (int n = 0; n < 4; ++n)
#pragma unroll
      for (int r = 0; r < 4; ++r) {
        const float relq = bf2f(gqp[(48 + r - 16 * n) * ST_R + r]);
        const float relk = bf2f(gkp[(48 + r - 16 * n) * ST_R + 16 * n]);
        const float pr = exp2f(fmaf(relk, 0.125f * 1.44269504f, aqk[n][r] + relq));
        kcur[SWZ(16 * w + 4 * g + r, 16 * n + li)] = f2bf_hw(pr);
      }

    // ---- O += P.V ; accX += P.1 (row-sum on matrix pipe) ----
    bf16x8 pA[2];
#pragma unroll
    for (int c = 0; c < 2; ++c)
      pA[c] = *reinterpret_cast<const bf16x8*>(&kcur[SWZ(16 * w + li, 32 * c + 8 * g)]);
#pragma unroll
    for (int n = 0; n < 4; ++n)
#pragma unroll
      for (int c = 0; c < 2; ++c)
        accO[n] = __builtin_amdgcn_mfma_f32_16x16x32_bf16(pA[c], vf[n][c], accO[n], 0, 0, 0);
#pragma unroll
    for (int c = 0; c < 2; ++c)
      accX = __builtin_amdgcn_mfma_f32_16x16x32_bf16(pA[c], ones, accX, 0, 0, 0);
  }

  // ---- epilogue: normalize (accX holds row-sums in every lane), store ----
#pragma unroll
  for (int r = 0; r < 4; ++r) {
    const float inv = 1.0f / accX[r];
    const size_t row = (size_t)(b * SEQ + q0 + 16 * w + 4 * g + r) * HID + h * HD;
#pragma unroll
    for (int n = 0; n < 4; ++n) out[row + 16 * n + li] = accO[n][r] * inv;
  }
}

extern "C" void kernel_launch(void* const* d_in, const int* in_sizes, int n_in,
                              void* d_out, int out_size, void* d_ws, size_t ws_size,
                              hipStream_t stream) {
  const float* hs = (const float*)d_in[0];
  const float* Wq = (const float*)d_in[1];
  const float* bq = (const float*)d_in[2];
  const float* Wk = (const float*)d_in[3];
  const float* bk = (const float*)d_in[4];
  const float* Wv = (const float*)d_in[5];
  const float* bv = (const float*)d_in[6];
  const float* de = (const float*)d_in[7];
  float* out = (float*)d_out;

  // Sizes: hs = 4,194,304 floats; W* = 1,048,576; de = 262,080.
  u16* Xb  = (u16*)d_ws;                 // 4,194,304 u16
  u16* Wqb = Xb + (size_t)4194304;       // 1,048,576 each
  u16* Wkb = Wqb + (size_t)1048576;
  u16* Wvb = Wkb + (size_t)1048576;
  u16* Qb  = Wvb + (size_t)1048576;      // 4,194,304 each
  u16* Kb  = Qb + (size_t)4194304;
  u16* Vb  = Kb + (size_t)4194304;
  u16* Eb  = Vb + (size_t)4194304;       // 262,080
  u16* Vtb = Xb;                         // alias: Xb dead after proj_mfma

  dim3 blk(256);
  hipLaunchKernelGGL(cvt_f32_bf16, dim3(512), blk, 0, stream, hs, Xb, 1048576);
  hipLaunchKernelGGL(cvt_f32_bf16, dim3(256), blk, 0, stream, Wq, Wqb, 262144);
  hipLaunchKernelGGL(cvt_f32_bf16, dim3(256), blk, 0, stream, Wk, Wkb, 262144);
  hipLaunchKernelGGL(cvt_f32_bf16, dim3(256), blk, 0, stream, Wv, Wvb, 262144);
  hipLaunchKernelGGL(cvt_f32_bf16, dim3(128), blk, 0, stream, de, Eb, 65520);

  hipLaunchKernelGGL(proj_mfma, dim3(24, 32), blk, 0, stream,
                     Xb, Wqb, Wkb, Wvb, bq, bk, bv, Qb, Kb, Vb);
  hipLaunchKernelGGL(transpose_v, dim3(SEQ / 64, NH, 2), blk, 0, stream, Vb, Vtb);
  hipLaunchKernelGGL(attn_mfma6, dim3(SEQ / 64, NH, 2), blk, 0, stream, Qb, Kb, Vtb, Eb, out);
}

// Round 11
// 250.368 us; speedup vs baseline: 1.2181x; 1.2181x over previous
//
#include <hip/hip_runtime.h>
#include <hip/hip_bf16.h>

#define NH 16
#define HD 64
#define SEQ 2048
#define HID 1024
#define MAXP 2048
#define ST_R 68   // u16 stride of transposed R tiles (mult of 4 for b64 writes)

typedef float f32x4 __attribute__((ext_vector_type(4)));
typedef short bf16x8 __attribute__((ext_vector_type(8)));
typedef unsigned short u16;
typedef unsigned short u16x8 __attribute__((ext_vector_type(8)));

// Scalar HW convert; compiler fuses adjacent pairs into v_cvt_pk_bf16_f32 (m240).
__device__ __forceinline__ u16 f2bf_hw(float x) {
  union { __hip_bfloat16 h; u16 u; } v;
  v.h = __float2bfloat16(x);
  return v.u;
}
__device__ __forceinline__ unsigned pk2(float a, float b) {
  return (unsigned)f2bf_hw(a) | ((unsigned)f2bf_hw(b) << 16);
}
__device__ __forceinline__ float bf2f(u16 h) {
  union { unsigned u; float f; } v; v.u = ((unsigned)h) << 16;
  return v.f;
}

// XOR-swizzle for bf16 tiles with 64-elem (128B) row stride.
#define SWZ(r, c) ((r) * 64 + ((((c) >> 3) ^ ((r) & 7)) << 3) + ((c) & 7))

// async global->LDS 16B: LDS dest = wave-uniform base + lane*16; global src per-lane.
__device__ __forceinline__ void async_copy16(void* lds, const void* g) {
  __builtin_amdgcn_global_load_lds(
      (const __attribute__((address_space(1))) unsigned int*)g,
      (__attribute__((address_space(3))) unsigned int*)lds, 16, 0, 0);
}
__device__ __forceinline__ void vwait0() { asm volatile("s_waitcnt vmcnt(0)" ::: "memory"); }
__device__ __forceinline__ void lwait0() { asm volatile("s_waitcnt lgkmcnt(0)" ::: "memory"); }

// ---------------- fused fp32 -> bf16 bulk convert (5 regions, 1 launch) ----------------
__global__ __launch_bounds__(256) void cvt_multi(
    const float* __restrict__ s0, const float* __restrict__ s1,
    const float* __restrict__ s2, const float* __restrict__ s3,
    const float* __restrict__ s4,
    u16* __restrict__ d0, u16* __restrict__ d1, u16* __restrict__ d2,
    u16* __restrict__ d3, u16* __restrict__ d4) {
  const float* s; u16* d; int n4;
  switch (blockIdx.y) {
    case 0: s = s0; d = d0; n4 = 1048576; break;   // hidden_states
    case 1: s = s1; d = d1; n4 = 262144; break;    // Wq
    case 2: s = s2; d = d2; n4 = 262144; break;    // Wk
    case 3: s = s3; d = d3; n4 = 262144; break;    // Wv
    default: s = s4; d = d4; n4 = 65520; break;    // dist_emb
  }
  int i = blockIdx.x * 256 + threadIdx.x;
  const int stride = gridDim.x * 256;
  for (; i < n4; i += stride) {
    const float4 v = reinterpret_cast<const float4*>(s)[i];
    uint2 o;
    o.x = pk2(v.x, v.y);
    o.y = pk2(v.z, v.w);
    reinterpret_cast<uint2*>(d)[i] = o;
  }
}

// ---------------- Fused Q/K/V projection: O = bf16((X @ W^T + b) * scale) ----
// Q (wsel==0) pre-scaled by 0.125*log2(e): folds 1/sqrt(64) AND exp->exp2.
__global__ __launch_bounds__(256) void proj_mfma(
    const u16* __restrict__ Xb, const u16* __restrict__ W0,
    const u16* __restrict__ W1, const u16* __restrict__ W2,
    const float* __restrict__ b0, const float* __restrict__ b1,
    const float* __restrict__ b2,
    u16* __restrict__ O0, u16* __restrict__ O1, u16* __restrict__ O2) {
  __shared__ u16 sA[128 * 64];
  __shared__ u16 sB[128 * 64];
  const int t = threadIdx.x, lane = t & 63, w = t >> 6;
  const int g = lane >> 4, li = lane & 15;
  const int wsel = blockIdx.x >> 3;
  const int n0 = (blockIdx.x & 7) * 128, m0 = blockIdx.y * 128;
  const u16* Wb = wsel == 0 ? W0 : (wsel == 1 ? W1 : W2);
  const float* bias = wsel == 0 ? b0 : (wsel == 1 ? b1 : b2);
  u16* Ob = wsel == 0 ? O0 : (wsel == 1 ? O1 : O2);
  const float oscale = wsel == 0 ? 0.125f * 1.44269504f : 1.0f;
  const int wr = w >> 1, wc = w & 1;

  f32x4 acc[4][4];
#pragma unroll
  for (int i = 0; i < 4; ++i)
#pragma unroll
    for (int j = 0; j < 4; ++j) acc[i][j] = (f32x4)0.0f;

  for (int k0 = 0; k0 < HID; k0 += 64) {
    __syncthreads();
#pragma unroll
    for (int i = 0; i < 4; ++i) {
      const int idx = (w * 4 + i) * 64 + lane;
      const int row = idx >> 3, sch = (idx & 7) ^ (row & 7);
      async_copy16(&sA[(w * 4 + i) * 512], Xb + (size_t)(m0 + row) * HID + k0 + sch * 8);
      async_copy16(&sB[(w * 4 + i) * 512], Wb + (size_t)(n0 + row) * HID + k0 + sch * 8);
    }
    __syncthreads();
    bf16x8 af[4][2], bfr[4][2];
#pragma unroll
    for (int i = 0; i < 4; ++i)
#pragma unroll
      for (int c = 0; c < 2; ++c)
        af[i][c] = *reinterpret_cast<const bf16x8*>(&sA[SWZ(wr * 64 + 16 * i + li, 32 * c + 8 * g)]);
#pragma unroll
    for (int j = 0; j < 4; ++j)
#pragma unroll
      for (int c = 0; c < 2; ++c)
        bfr[j][c] = *reinterpret_cast<const bf16x8*>(&sB[SWZ(wc * 64 + 16 * j + li, 32 * c + 8 * g)]);
#pragma unroll
    for (int i = 0; i < 4; ++i)
#pragma unroll
      for (int j = 0; j < 4; ++j)
#pragma unroll
        for (int c = 0; c < 2; ++c)
          acc[i][j] = __builtin_amdgcn_mfma_f32_16x16x32_bf16(af[i][c], bfr[j][c], acc[i][j], 0, 0, 0);
  }

#pragma unroll
  for (int j = 0; j < 4; ++j) {
    const float bj = bias[n0 + wc * 64 + 16 * j + li];
#pragma unroll
    for (int i = 0; i < 4; ++i)
#pragma unroll
      for (int r = 0; r < 4; ++r)
        Ob[(size_t)(m0 + wr * 64 + 16 * i + 4 * g + r) * HID + n0 + wc * 64 + 16 * j + li] =
            f2bf_hw((acc[i][j][r] + bj) * oscale);
  }
}

// ---------------- V transpose: Vt[b][h][d][s] <- V[b][s][h*64+d] ----------------
__global__ __launch_bounds__(256) void transpose_v(
    const u16* __restrict__ Vin, u16* __restrict__ Vt) {
  __shared__ u16 tile[64 * 65];
  const int t = threadIdx.x;
  const int s0 = blockIdx.x * 64, h = blockIdx.y, b = blockIdx.z;
  const int r = t >> 2, c0 = (t & 3) * 16;
  const u16* gp = Vin + (size_t)(b * SEQ + s0 + r) * HID + h * HD + c0;
  const u16x8 a0 = *reinterpret_cast<const u16x8*>(gp);
  const u16x8 a1 = *reinterpret_cast<const u16x8*>(gp + 8);
#pragma unroll
  for (int i = 0; i < 8; ++i) { tile[r * 65 + c0 + i] = a0[i]; tile[r * 65 + c0 + 8 + i] = a1[i]; }
  __syncthreads();
  const int d = t >> 2, sc = (t & 3) * 16;
  u16x8 o0, o1;
#pragma unroll
  for (int i = 0; i < 8; ++i) {
    o0[i] = tile[(sc + i) * 65 + d];
    o1[i] = tile[(sc + 8 + i) * 65 + d];
  }
  u16* op = Vt + ((size_t)(b * NH + h) * HD + d) * SEQ + s0 + sc;
  *reinterpret_cast<u16x8*>(op) = o0;
  *reinterpret_cast<u16x8*>(op + 8) = o1;
}

// ---------------- Fused MFMA attention v7 ----------------
// R8's 2-barrier pipeline (V staged via gload_lds — R10's per-wave V-to-reg
// quadrupled L2 traffic and regressed) + exp2-folded softmax + accX ones-MFMA
// denominator + scores/PV half-interleave + setprio around MFMA clusters.
__global__ __launch_bounds__(256, 2) void attn_mfma7(
    const u16* __restrict__ Q, const u16* __restrict__ K,
    const u16* __restrict__ Vt, const u16* __restrict__ E,
    float* __restrict__ out) {
  __shared__ u16 sK0[64 * 64];     // K buffers; current one becomes P after #2
  __shared__ u16 sK1[64 * 64];
  __shared__ u16 sV[64 * 64];
  __shared__ u16 sE[128 * 64];
  __shared__ u16 sRq[128 * ST_R];  // [j][qi] transposed
  __shared__ u16 sRk[128 * ST_R];  // [j][ki]

  const int t = threadIdx.x;
  const int lane = t & 63, w = t >> 6;
  const int g = lane >> 4, li = lane & 15;
  const int q0 = blockIdx.x * 64;
  const int h = blockIdx.y, b = blockIdx.z;
  const size_t qkbase = (size_t)b * SEQ * HID + (size_t)h * HD;
  const size_t vtbase = (size_t)(b * NH + h) * HD * SEQ;

  bf16x8 qA[2];
#pragma unroll
  for (int c = 0; c < 2; ++c)
    qA[c] = *reinterpret_cast<const bf16x8*>(
        Q + qkbase + (size_t)(q0 + 16 * w + li) * HID + 32 * c + 8 * g);

  bf16x8 ones;
#pragma unroll
  for (int i = 0; i < 8; ++i) ones[i] = (short)0x3F80;  // bf16 1.0

  f32x4 accO[4];
  f32x4 accX = (f32x4)0.0f;   // row-sum of P (denominator) via ones-MFMA
#pragma unroll
  for (int n = 0; n < 4; ++n) accO[n] = (f32x4)0.0f;

  // k0-invariant gather/write bases; j = 63+qi-ki, biased so unrolled offsets
  // are non-negative compile-time constants.
  const int jb48 = 15 + 16 * w + 4 * g - li;             // in [0, 75]
  const u16* gqp = &sRq[jb48 * ST_R + 16 * w + 4 * g];   // + (48+r-16n)*ST_R + r
  const u16* gkp = &sRk[jb48 * ST_R + li];               // + (48+r-16n)*ST_R + 16n
  u16* rkw = &sRk[li * ST_R + 16 * w + 4 * g];           // + m*16*ST_R
  u16* rqw = &sRq[li * ST_R + 16 * w + 4 * g];

  const int sidx2 = w * 2 * 64 + lane;
  const int sidx4 = w * 4 * 64 + lane;

  // ---- prologue: stage K(0), E(0); drain ----
  {
    const int eb0 = 1984 + q0;
#pragma unroll
    for (int i = 0; i < 2; ++i) {
      const int idx = sidx2 + i * 64;
      const int row = idx >> 3, sch = (idx & 7) ^ (row & 7);
      async_copy16(&sK0[(w * 2 + i) * 512], K + qkbase + (size_t)row * HID + sch * 8);
    }
#pragma unroll
    for (int i = 0; i < 4; ++i) {
      const int idx = sidx4 + i * 64;
      const int row = idx >> 3, sch = (idx & 7) ^ (row & 7);
      const int er = min(max(eb0 + row, 0), 2 * MAXP - 2);
      async_copy16(&sE[(w * 4 + i) * 512], E + (size_t)er * HD + sch * 8);
    }
    vwait0();
  }

  for (int k0 = 0; k0 < SEQ; k0 += 64) {
    const int p = (k0 >> 6) & 1;
    u16* kcur = p ? sK1 : sK0;
    u16* knxt = p ? sK0 : sK1;

    __builtin_amdgcn_s_barrier();   // #1: K(t),E(t) visible; knxt/sV reusable
    // ---- issue V(t) staging and K(t+1) staging ----
#pragma unroll
    for (int i = 0; i < 2; ++i) {
      const int idx = sidx2 + i * 64;
      const int row = idx >> 3, sch = (idx & 7) ^ (row & 7);
      async_copy16(&sV[(w * 2 + i) * 512], Vt + vtbase + (size_t)row * SEQ + k0 + sch * 8);
      async_copy16(&knxt[(w * 2 + i) * 512], K + qkbase + (size_t)(k0 + 64 + row) * HID + sch * 8);
    }

    // ---- S = Q'.K^T ----
    bf16x8 kA[2];
#pragma unroll
    for (int c = 0; c < 2; ++c)
      kA[c] = *reinterpret_cast<const bf16x8*>(&kcur[SWZ(16 * w + li, 32 * c + 8 * g)]);
    f32x4 aqk[4];
#pragma unroll
    for (int n = 0; n < 4; ++n) {
      aqk[n] = (f32x4)0.0f;
#pragma unroll
      for (int c = 0; c < 2; ++c) {
        const bf16x8 kB = *reinterpret_cast<const bf16x8*>(&kcur[SWZ(16 * n + li, 32 * c + 8 * g)]);
        aqk[n] = __builtin_amdgcn_mfma_f32_16x16x32_bf16(qA[c], kB, aqk[n], 0, 0, 0);
      }
    }
    // ---- Rq = Q'.E^T, Rk = K.E^T; packed b64 writes, transposed [j][col] ----
    __builtin_amdgcn_s_setprio(1);
#pragma unroll
    for (int m = 0; m < 8; ++m) {
      bf16x8 eB[2];
#pragma unroll
      for (int c = 0; c < 2; ++c)
        eB[c] = *reinterpret_cast<const bf16x8*>(&sE[SWZ(16 * m + li, 32 * c + 8 * g)]);
      f32x4 ak = (f32x4)0.0f, aq = (f32x4)0.0f;
#pragma unroll
      for (int c = 0; c < 2; ++c) {
        ak = __builtin_amdgcn_mfma_f32_16x16x32_bf16(kA[c], eB[c], ak, 0, 0, 0);
        aq = __builtin_amdgcn_mfma_f32_16x16x32_bf16(qA[c], eB[c], aq, 0, 0, 0);
      }
      uint2 dk, dq;
      dk.x = pk2(ak[0], ak[1]); dk.y = pk2(ak[2], ak[3]);
      dq.x = pk2(aq[0], aq[1]); dq.y = pk2(aq[2], aq[3]);
      *reinterpret_cast<uint2*>(rkw + m * 16 * ST_R) = dk;
      *reinterpret_cast<uint2*>(rqw + m * 16 * ST_R) = dq;
    }
    __builtin_amdgcn_s_setprio(0);

    vwait0();                       // V(t), K(t+1) landed (in flight since top)
    lwait0();                       // R-writes retired
    __builtin_amdgcn_s_barrier();   // #2: sRk/sRq + sV + K(t+1) visible to all

    // ---- issue E(t+1) (all sE reads happened before #2) ----
    {
      const int ebn = 1920 + q0 - k0;  // eb(t+1)
#pragma unroll
      for (int i = 0; i < 4; ++i) {
        const int idx = sidx4 + i * 64;
        const int row = idx >> 3, sch = (idx & 7) ^ (row & 7);
        const int er = min(max(ebn + row, 0), 2 * MAXP - 2);
        async_copy16(&sE[(w * 4 + i) * 512], E + (size_t)er * HD + sch * 8);
      }
    }

    // ---- scores/PV half-interleave: write P n={0,1} -> PV c=0 while n={2,3} ----
#pragma unroll
    for (int half = 0; half < 2; ++half) {
#pragma unroll
      for (int nn = 0; nn < 2; ++nn) {
        const int n = half * 2 + nn;
#pragma unroll
        for (int r = 0; r < 4; ++r) {
          const float relq = bf2f(gqp[(48 + r - 16 * n) * ST_R + r]);
          const float relk = bf2f(gkp[(48 + r - 16 * n) * ST_R + 16 * n]);
          const float pr = exp2f(fmaf(relk, 0.125f * 1.44269504f, aqk[n][r] + relq));
          kcur[SWZ(16 * w + 4 * g + r, 16 * n + li)] = f2bf_hw(pr);
        }
      }
      // P cols [32*half, 32*half+31] complete for this wave's rows -> PV c=half
      const bf16x8 pA = *reinterpret_cast<const bf16x8*>(
          &kcur[SWZ(16 * w + li, 32 * half + 8 * g)]);
      __builtin_amdgcn_s_setprio(1);
#pragma unroll
      for (int n = 0; n < 4; ++n) {
        const bf16x8 vB = *reinterpret_cast<const bf16x8*>(
            &sV[SWZ(16 * n + li, 32 * half + 8 * g)]);
        accO[n] = __builtin_amdgcn_mfma_f32_16x16x32_bf16(pA, vB, accO[n], 0, 0, 0);
      }
      accX = __builtin_amdgcn_mfma_f32_16x16x32_bf16(pA, ones, accX, 0, 0, 0);
      __builtin_amdgcn_s_setprio(0);
    }

    vwait0();                       // E(t+1) landed (in flight since #2)
  }

  // ---- epilogue: normalize (accX holds row-sums in every lane), store ----
#pragma unroll
  for (int r = 0; r < 4; ++r) {
    const float inv = 1.0f / accX[r];
    const size_t row = (size_t)(b * SEQ + q0 + 16 * w + 4 * g + r) * HID + h * HD;
#pragma unroll
    for (int n = 0; n < 4; ++n) out[row + 16 * n + li] = accO[n][r] * inv;
  }
}

extern "C" void kernel_launch(void* const* d_in, const int* in_sizes, int n_in,
                              void* d_out, int out_size, void* d_ws, size_t ws_size,
                              hipStream_t stream) {
  const float* hs = (const float*)d_in[0];
  const float* Wq = (const float*)d_in[1];
  const float* bq = (const float*)d_in[2];
  const float* Wk = (const float*)d_in[3];
  const float* bk = (const float*)d_in[4];
  const float* Wv = (const float*)d_in[5];
  const float* bv = (const float*)d_in[6];
  const float* de = (const float*)d_in[7];
  float* out = (float*)d_out;

  // Sizes: hs = 4,194,304 floats; W* = 1,048,576; de = 262,080.
  u16* Xb  = (u16*)d_ws;                 // 4,194,304 u16
  u16* Wqb = Xb + (size_t)4194304;       // 1,048,576 each
  u16* Wkb = Wqb + (size_t)1048576;
  u16* Wvb = Wkb + (size_t)1048576;
  u16* Qb  = Wvb + (size_t)1048576;      // 4,194,304 each
  u16* Kb  = Qb + (size_t)4194304;
  u16* Vb  = Kb + (size_t)4194304;
  u16* Eb  = Vb + (size_t)4194304;       // 262,080
  u16* Vtb = Xb;                         // alias: Xb dead after proj_mfma

  dim3 blk(256);
  hipLaunchKernelGGL(cvt_multi, dim3(1024, 5), blk, 0, stream,
                     hs, Wq, Wk, Wv, de, Xb, Wqb, Wkb, Wvb, Eb);
  hipLaunchKernelGGL(proj_mfma, dim3(24, 32), blk, 0, stream,
                     Xb, Wqb, Wkb, Wvb, bq, bk, bv, Qb, Kb, Vb);
  hipLaunchKernelGGL(transpose_v, dim3(SEQ / 64, NH, 2), blk, 0, stream, Vb, Vtb);
  hipLaunchKernelGGL(attn_mfma7, dim3(SEQ / 64, NH, 2), blk, 0, stream, Qb, Kb, Vtb, Eb, out);
}

// Round 12
// 246.089 us; speedup vs baseline: 1.2393x; 1.0174x over previous
//
#include <hip/hip_runtime.h>
#include <hip/hip_bf16.h>

#define NH 16
#define HD 64
#define SEQ 2048
#define HID 1024
#define MAXP 2048
#define ST_R 68   // u16 stride of transposed R tiles (mult of 4 for b64 writes)

typedef float f32x4 __attribute__((ext_vector_type(4)));
typedef short bf16x8 __attribute__((ext_vector_type(8)));
typedef unsigned short u16;
typedef unsigned short u16x8 __attribute__((ext_vector_type(8)));

// Scalar HW convert; compiler fuses adjacent pairs into v_cvt_pk_bf16_f32 (m240).
__device__ __forceinline__ u16 f2bf_hw(float x) {
  union { __hip_bfloat16 h; u16 u; } v;
  v.h = __float2bfloat16(x);
  return v.u;
}
__device__ __forceinline__ unsigned pk2(float a, float b) {
  return (unsigned)f2bf_hw(a) | ((unsigned)f2bf_hw(b) << 16);
}
__device__ __forceinline__ float bf2f(u16 h) {
  union { unsigned u; float f; } v; v.u = ((unsigned)h) << 16;
  return v.f;
}

// XOR-swizzle for bf16 tiles with 64-elem (128B) row stride.
#define SWZ(r, c) ((r) * 64 + ((((c) >> 3) ^ ((r) & 7)) << 3) + ((c) & 7))

// async global->LDS 16B: LDS dest = wave-uniform base + lane*16; global src per-lane.
__device__ __forceinline__ void async_copy16(void* lds, const void* g) {
  __builtin_amdgcn_global_load_lds(
      (const __attribute__((address_space(1))) unsigned int*)g,
      (__attribute__((address_space(3))) unsigned int*)lds, 16, 0, 0);
}
__device__ __forceinline__ void vwait0() { asm volatile("s_waitcnt vmcnt(0)" ::: "memory"); }
__device__ __forceinline__ void lwait0() { asm volatile("s_waitcnt lgkmcnt(0)" ::: "memory"); }

// ---------------- fused fp32 -> bf16 bulk convert (5 regions, 1 launch) ----------------
__global__ __launch_bounds__(256) void cvt_multi(
    const float* __restrict__ s0, const float* __restrict__ s1,
    const float* __restrict__ s2, const float* __restrict__ s3,
    const float* __restrict__ s4,
    u16* __restrict__ d0, u16* __restrict__ d1, u16* __restrict__ d2,
    u16* __restrict__ d3, u16* __restrict__ d4) {
  const float* s; u16* d; int n4;
  switch (blockIdx.y) {
    case 0: s = s0; d = d0; n4 = 1048576; break;   // hidden_states
    case 1: s = s1; d = d1; n4 = 262144; break;    // Wq
    case 2: s = s2; d = d2; n4 = 262144; break;    // Wk
    case 3: s = s3; d = d3; n4 = 262144; break;    // Wv
    default: s = s4; d = d4; n4 = 65520; break;    // dist_emb
  }
  int i = blockIdx.x * 256 + threadIdx.x;
  const int stride = gridDim.x * 256;
  for (; i < n4; i += stride) {
    const float4 v = reinterpret_cast<const float4*>(s)[i];
    uint2 o;
    o.x = pk2(v.x, v.y);
    o.y = pk2(v.z, v.w);
    reinterpret_cast<uint2*>(d)[i] = o;
  }
}

// ---------------- Fused Q/K/V projection: O = bf16((X @ W^T + b) * scale) ----
// Q (wsel==0) pre-scaled by 0.125*log2(e): folds 1/sqrt(64) AND exp->exp2.
__global__ __launch_bounds__(256) void proj_mfma(
    const u16* __restrict__ Xb, const u16* __restrict__ W0,
    const u16* __restrict__ W1, const u16* __restrict__ W2,
    const float* __restrict__ b0, const float* __restrict__ b1,
    const float* __restrict__ b2,
    u16* __restrict__ O0, u16* __restrict__ O1, u16* __restrict__ O2) {
  __shared__ u16 sA[128 * 64];
  __shared__ u16 sB[128 * 64];
  const int t = threadIdx.x, lane = t & 63, w = t >> 6;
  const int g = lane >> 4, li = lane & 15;
  const int wsel = blockIdx.x >> 3;
  const int n0 = (blockIdx.x & 7) * 128, m0 = blockIdx.y * 128;
  const u16* Wb = wsel == 0 ? W0 : (wsel == 1 ? W1 : W2);
  const float* bias = wsel == 0 ? b0 : (wsel == 1 ? b1 : b2);
  u16* Ob = wsel == 0 ? O0 : (wsel == 1 ? O1 : O2);
  const float oscale = wsel == 0 ? 0.125f * 1.44269504f : 1.0f;
  const int wr = w >> 1, wc = w & 1;

  f32x4 acc[4][4];
#pragma unroll
  for (int i = 0; i < 4; ++i)
#pragma unroll
    for (int j = 0; j < 4; ++j) acc[i][j] = (f32x4)0.0f;

  for (int k0 = 0; k0 < HID; k0 += 64) {
    __syncthreads();
#pragma unroll
    for (int i = 0; i < 4; ++i) {
      const int idx = (w * 4 + i) * 64 + lane;
      const int row = idx >> 3, sch = (idx & 7) ^ (row & 7);
      async_copy16(&sA[(w * 4 + i) * 512], Xb + (size_t)(m0 + row) * HID + k0 + sch * 8);
      async_copy16(&sB[(w * 4 + i) * 512], Wb + (size_t)(n0 + row) * HID + k0 + sch * 8);
    }
    __syncthreads();
    bf16x8 af[4][2], bfr[4][2];
#pragma unroll
    for (int i = 0; i < 4; ++i)
#pragma unroll
      for (int c = 0; c < 2; ++c)
        af[i][c] = *reinterpret_cast<const bf16x8*>(&sA[SWZ(wr * 64 + 16 * i + li, 32 * c + 8 * g)]);
#pragma unroll
    for (int j = 0; j < 4; ++j)
#pragma unroll
      for (int c = 0; c < 2; ++c)
        bfr[j][c] = *reinterpret_cast<const bf16x8*>(&sB[SWZ(wc * 64 + 16 * j + li, 32 * c + 8 * g)]);
#pragma unroll
    for (int i = 0; i < 4; ++i)
#pragma unroll
      for (int j = 0; j < 4; ++j)
#pragma unroll
        for (int c = 0; c < 2; ++c)
          acc[i][j] = __builtin_amdgcn_mfma_f32_16x16x32_bf16(af[i][c], bfr[j][c], acc[i][j], 0, 0, 0);
  }

#pragma unroll
  for (int j = 0; j < 4; ++j) {
    const float bj = bias[n0 + wc * 64 + 16 * j + li];
#pragma unroll
    for (int i = 0; i < 4; ++i)
#pragma unroll
      for (int r = 0; r < 4; ++r)
        Ob[(size_t)(m0 + wr * 64 + 16 * i + 4 * g + r) * HID + n0 + wc * 64 + 16 * j + li] =
            f2bf_hw((acc[i][j][r] + bj) * oscale);
  }
}

// ---------------- V transpose: Vt[b][h][d][s] <- V[b][s][h*64+d] ----------------
__global__ __launch_bounds__(256) void transpose_v(
    const u16* __restrict__ Vin, u16* __restrict__ Vt) {
  __shared__ u16 tile[64 * 65];
  const int t = threadIdx.x;
  const int s0 = blockIdx.x * 64, h = blockIdx.y, b = blockIdx.z;
  const int r = t >> 2, c0 = (t & 3) * 16;
  const u16* gp = Vin + (size_t)(b * SEQ + s0 + r) * HID + h * HD + c0;
  const u16x8 a0 = *reinterpret_cast<const u16x8*>(gp);
  const u16x8 a1 = *reinterpret_cast<const u16x8*>(gp + 8);
#pragma unroll
  for (int i = 0; i < 8; ++i) { tile[r * 65 + c0 + i] = a0[i]; tile[r * 65 + c0 + 8 + i] = a1[i]; }
  __syncthreads();
  const int d = t >> 2, sc = (t & 3) * 16;
  u16x8 o0, o1;
#pragma unroll
  for (int i = 0; i < 8; ++i) {
    o0[i] = tile[(sc + i) * 65 + d];
    o1[i] = tile[(sc + 8 + i) * 65 + d];
  }
  u16* op = Vt + ((size_t)(b * NH + h) * HD + d) * SEQ + s0 + sc;
  *reinterpret_cast<u16x8*>(op) = o0;
  *reinterpret_cast<u16x8*>(op + 8) = o1;
}

// ---------------- Fused MFMA attention v8 ----------------
// Exact R8 skeleton (2-barrier pipeline, full scores phase then single PV
// phase, setprio ONLY around the R-GEMM cluster) + verified VALU cuts:
// exp2-folded softmax (Q pre-scaled 0.125*log2e) and accX ones-MFMA
// denominator. R11's half-interleave + PV-setprio regressed and are reverted.
__global__ __launch_bounds__(256, 2) void attn_mfma8(
    const u16* __restrict__ Q, const u16* __restrict__ K,
    const u16* __restrict__ Vt, const u16* __restrict__ E,
    float* __restrict__ out) {
  __shared__ u16 sK0[64 * 64];     // K buffers; current one becomes P after #2
  __shared__ u16 sK1[64 * 64];
  __shared__ u16 sV[64 * 64];
  __shared__ u16 sE[128 * 64];
  __shared__ u16 sRq[128 * ST_R];  // [j][qi] transposed
  __shared__ u16 sRk[128 * ST_R];  // [j][ki]

  const int t = threadIdx.x;
  const int lane = t & 63, w = t >> 6;
  const int g = lane >> 4, li = lane & 15;
  const int q0 = blockIdx.x * 64;
  const int h = blockIdx.y, b = blockIdx.z;
  const size_t qkbase = (size_t)b * SEQ * HID + (size_t)h * HD;
  const size_t vtbase = (size_t)(b * NH + h) * HD * SEQ;

  bf16x8 qA[2];
#pragma unroll
  for (int c = 0; c < 2; ++c)
    qA[c] = *reinterpret_cast<const bf16x8*>(
        Q + qkbase + (size_t)(q0 + 16 * w + li) * HID + 32 * c + 8 * g);

  bf16x8 ones;
#pragma unroll
  for (int i = 0; i < 8; ++i) ones[i] = (short)0x3F80;  // bf16 1.0

  f32x4 accO[4];
  f32x4 accX = (f32x4)0.0f;   // row-sum of P (denominator) via ones-MFMA
#pragma unroll
  for (int n = 0; n < 4; ++n) accO[n] = (f32x4)0.0f;

  // k0-invariant gather/write bases; j = 63+qi-ki, biased so unrolled offsets
  // are non-negative compile-time constants.
  const int jb48 = 15 + 16 * w + 4 * g - li;             // in [0, 75]
  const u16* gqp = &sRq[jb48 * ST_R + 16 * w + 4 * g];   // + (48+r-16n)*ST_R + r
  const u16* gkp = &sRk[jb48 * ST_R + li];               // + (48+r-16n)*ST_R + 16n
  u16* rkw = &sRk[li * ST_R + 16 * w + 4 * g];           // + m*16*ST_R
  u16* rqw = &sRq[li * ST_R + 16 * w + 4 * g];

  const int sidx2 = w * 2 * 64 + lane;
  const int sidx4 = w * 4 * 64 + lane;

  // ---- prologue: stage K(0), E(0); drain ----
  {
    const int eb0 = 1984 + q0;
#pragma unroll
    for (int i = 0; i < 2; ++i) {
      const int idx = sidx2 + i * 64;
      const int row = idx >> 3, sch = (idx & 7) ^ (row & 7);
      async_copy16(&sK0[(w * 2 + i) * 512], K + qkbase + (size_t)row * HID + sch * 8);
    }
#pragma unroll
    for (int i = 0; i < 4; ++i) {
      const int idx = sidx4 + i * 64;
      const int row = idx >> 3, sch = (idx & 7) ^ (row & 7);
      const int er = min(max(eb0 + row, 0), 2 * MAXP - 2);
      async_copy16(&sE[(w * 4 + i) * 512], E + (size_t)er * HD + sch * 8);
    }
    vwait0();
  }

  for (int k0 = 0; k0 < SEQ; k0 += 64) {
    const int p = (k0 >> 6) & 1;
    u16* kcur = p ? sK1 : sK0;
    u16* knxt = p ? sK0 : sK1;

    __builtin_amdgcn_s_barrier();   // #1: K(t),E(t) visible; knxt/sV reusable
    // ---- issue V(t) staging and K(t+1) staging ----
#pragma unroll
    for (int i = 0; i < 2; ++i) {
      const int idx = sidx2 + i * 64;
      const int row = idx >> 3, sch = (idx & 7) ^ (row & 7);
      async_copy16(&sV[(w * 2 + i) * 512], Vt + vtbase + (size_t)row * SEQ + k0 + sch * 8);
      async_copy16(&knxt[(w * 2 + i) * 512], K + qkbase + (size_t)(k0 + 64 + row) * HID + sch * 8);
    }

    // ---- S = Q'.K^T ----
    bf16x8 kA[2];
#pragma unroll
    for (int c = 0; c < 2; ++c)
      kA[c] = *reinterpret_cast<const bf16x8*>(&kcur[SWZ(16 * w + li, 32 * c + 8 * g)]);
    f32x4 aqk[4];
#pragma unroll
    for (int n = 0; n < 4; ++n) {
      aqk[n] = (f32x4)0.0f;
#pragma unroll
      for (int c = 0; c < 2; ++c) {
        const bf16x8 kB = *reinterpret_cast<const bf16x8*>(&kcur[SWZ(16 * n + li, 32 * c + 8 * g)]);
        aqk[n] = __builtin_amdgcn_mfma_f32_16x16x32_bf16(qA[c], kB, aqk[n], 0, 0, 0);
      }
    }
    // ---- Rq = Q'.E^T, Rk = K.E^T; packed b64 writes, transposed [j][col] ----
    __builtin_amdgcn_s_setprio(1);
#pragma unroll
    for (int m = 0; m < 8; ++m) {
      bf16x8 eB[2];
#pragma unroll
      for (int c = 0; c < 2; ++c)
        eB[c] = *reinterpret_cast<const bf16x8*>(&sE[SWZ(16 * m + li, 32 * c + 8 * g)]);
      f32x4 ak = (f32x4)0.0f, aq = (f32x4)0.0f;
#pragma unroll
      for (int c = 0; c < 2; ++c) {
        ak = __builtin_amdgcn_mfma_f32_16x16x32_bf16(kA[c], eB[c], ak, 0, 0, 0);
        aq = __builtin_amdgcn_mfma_f32_16x16x32_bf16(qA[c], eB[c], aq, 0, 0, 0);
      }
      uint2 dk, dq;
      dk.x = pk2(ak[0], ak[1]); dk.y = pk2(ak[2], ak[3]);
      dq.x = pk2(aq[0], aq[1]); dq.y = pk2(aq[2], aq[3]);
      *reinterpret_cast<uint2*>(rkw + m * 16 * ST_R) = dk;
      *reinterpret_cast<uint2*>(rqw + m * 16 * ST_R) = dq;
    }
    __builtin_amdgcn_s_setprio(0);

    vwait0();                       // V(t), K(t+1) landed (in flight since top)
    lwait0();                       // R-writes retired
    __builtin_amdgcn_s_barrier();   // #2: sRk/sRq + sV + K(t+1) visible to all

    // ---- issue E(t+1) (all sE reads happened before #2) ----
    {
      const int ebn = 1920 + q0 - k0;  // eb(t+1)
#pragma unroll
      for (int i = 0; i < 4; ++i) {
        const int idx = sidx4 + i * 64;
        const int row = idx >> 3, sch = (idx & 7) ^ (row & 7);
        const int er = min(max(ebn + row, 0), 2 * MAXP - 2);
        async_copy16(&sE[(w * 4 + i) * 512], E + (size_t)er * HD + sch * 8);
      }
    }

    // ---- scores: gather + exp2 + P write (into kcur, dead K tile) ----
#pragma unroll
    for (int n = 0; n < 4; ++n)
#pragma unroll
      for (int r = 0; r < 4; ++r) {
        const float relq = bf2f(gqp[(48 + r - 16 * n) * ST_R + r]);
        const float relk = bf2f(gkp[(48 + r - 16 * n) * ST_R + 16 * n]);
        const float pr = exp2f(fmaf(relk, 0.125f * 1.44269504f, aqk[n][r] + relq));
        kcur[SWZ(16 * w + 4 * g + r, 16 * n + li)] = f2bf_hw(pr);
      }

    // ---- O += P.V ; accX += P.1 (row-sum on matrix pipe) ----
    bf16x8 pA[2];
#pragma unroll
    for (int c = 0; c < 2; ++c)
      pA[c] = *reinterpret_cast<const bf16x8*>(&kcur[SWZ(16 * w + li, 32 * c + 8 * g)]);
#pragma unroll
    for (int n = 0; n < 4; ++n)
#pragma unroll
      for (int c = 0; c < 2; ++c) {
        const bf16x8 vB = *reinterpret_cast<const bf16x8*>(&sV[SWZ(16 * n + li, 32 * c + 8 * g)]);
        accO[n] = __builtin_amdgcn_mfma_f32_16x16x32_bf16(pA[c], vB, accO[n], 0, 0, 0);
      }
#pragma unroll
    for (int c = 0; c < 2; ++c)
      accX = __builtin_amdgcn_mfma_f32_16x16x32_bf16(pA[c], ones, accX, 0, 0, 0);

    vwait0();                       // E(t+1) landed (in flight since #2)
  }

  // ---- epilogue: normalize (accX holds row-sums in every lane), store ----
#pragma unroll
  for (int r = 0; r < 4; ++r) {
    const float inv = 1.0f / accX[r];
    const size_t row = (size_t)(b * SEQ + q0 + 16 * w + 4 * g + r) * HID + h * HD;
#pragma unroll
    for (int n = 0; n < 4; ++n) out[row + 16 * n + li] = accO[n][r] * inv;
  }
}

extern "C" void kernel_launch(void* const* d_in, const int* in_sizes, int n_in,
                              void* d_out, int out_size, void* d_ws, size_t ws_size,
                              hipStream_t stream) {
  const float* hs = (const float*)d_in[0];
  const float* Wq = (const float*)d_in[1];
  const float* bq = (const float*)d_in[2];
  const float* Wk = (const float*)d_in[3];
  const float* bk = (const float*)d_in[4];
  const float* Wv = (const float*)d_in[5];
  const float* bv = (const float*)d_in[6];
  const float* de = (const float*)d_in[7];
  float* out = (float*)d_out;

  // Sizes: hs = 4,194,304 floats; W* = 1,048,576; de = 262,080.
  u16* Xb  = (u16*)d_ws;                 // 4,194,304 u16
  u16* Wqb = Xb + (size_t)4194304;       // 1,048,576 each
  u16* Wkb = Wqb + (size_t)1048576;
  u16* Wvb = Wkb + (size_t)1048576;
  u16* Qb  = Wvb + (size_t)1048576;      // 4,194,304 each
  u16* Kb  = Qb + (size_t)4194304;
  u16* Vb  = Kb + (size_t)4194304;
  u16* Eb  = Vb + (size_t)4194304;       // 262,080
  u16* Vtb = Xb;                         // alias: Xb dead after proj_mfma

  dim3 blk(256);
  hipLaunchKernelGGL(cvt_multi, dim3(1024, 5), blk, 0, stream,
                     hs, Wq, Wk, Wv, de, Xb, Wqb, Wkb, Wvb, Eb);
  hipLaunchKernelGGL(proj_mfma, dim3(24, 32), blk, 0, stream,
                     Xb, Wqb, Wkb, Wvb, bq, bk, bv, Qb, Kb, Vb);
  hipLaunchKernelGGL(transpose_v, dim3(SEQ / 64, NH, 2), blk, 0, stream, Vb, Vtb);
  hipLaunchKernelGGL(attn_mfma8, dim3(SEQ / 64, NH, 2), blk, 0, stream, Qb, Kb, Vtb, Eb, out);
}

// Round 13
// 234.265 us; speedup vs baseline: 1.3018x; 1.0505x over previous
//
#include <hip/hip_runtime.h>
#include <hip/hip_bf16.h>

#define NH 16
#define HD 64
#define SEQ 2048
#define HID 1024
#define MAXP 2048
#define ST_R 76   // u16 stride of transposed R tiles; 152B rows: b64-aligned,
                  // and 6*li mod 32 covers all 16 even banks once -> 2-way reads

typedef float f32x4 __attribute__((ext_vector_type(4)));
typedef short bf16x8 __attribute__((ext_vector_type(8)));
typedef unsigned short u16;
typedef unsigned short u16x8 __attribute__((ext_vector_type(8)));

// Scalar HW convert; compiler fuses adjacent pairs into v_cvt_pk_bf16_f32 (m240).
__device__ __forceinline__ u16 f2bf_hw(float x) {
  union { __hip_bfloat16 h; u16 u; } v;
  v.h = __float2bfloat16(x);
  return v.u;
}
__device__ __forceinline__ unsigned pk2(float a, float b) {
  return (unsigned)f2bf_hw(a) | ((unsigned)f2bf_hw(b) << 16);
}
__device__ __forceinline__ float bf2f(u16 h) {
  union { unsigned u; float f; } v; v.u = ((unsigned)h) << 16;
  return v.f;
}

// XOR-swizzle for bf16 tiles with 64-elem (128B) row stride.
#define SWZ(r, c) ((r) * 64 + ((((c) >> 3) ^ ((r) & 7)) << 3) + ((c) & 7))

// async global->LDS 16B: LDS dest = wave-uniform base + lane*16; global src per-lane.
__device__ __forceinline__ void async_copy16(void* lds, const void* g) {
  __builtin_amdgcn_global_load_lds(
      (const __attribute__((address_space(1))) unsigned int*)g,
      (__attribute__((address_space(3))) unsigned int*)lds, 16, 0, 0);
}
__device__ __forceinline__ void vwait0() { asm volatile("s_waitcnt vmcnt(0)" ::: "memory"); }
__device__ __forceinline__ void lwait0() { asm volatile("s_waitcnt lgkmcnt(0)" ::: "memory"); }

// ---------------- fused fp32 -> bf16 bulk convert (5 regions, 1 launch) ----------------
__global__ __launch_bounds__(256) void cvt_multi(
    const float* __restrict__ s0, const float* __restrict__ s1,
    const float* __restrict__ s2, const float* __restrict__ s3,
    const float* __restrict__ s4,
    u16* __restrict__ d0, u16* __restrict__ d1, u16* __restrict__ d2,
    u16* __restrict__ d3, u16* __restrict__ d4) {
  const float* s; u16* d; int n4;
  switch (blockIdx.y) {
    case 0: s = s0; d = d0; n4 = 1048576; break;   // hidden_states
    case 1: s = s1; d = d1; n4 = 262144; break;    // Wq
    case 2: s = s2; d = d2; n4 = 262144; break;    // Wk
    case 3: s = s3; d = d3; n4 = 262144; break;    // Wv
    default: s = s4; d = d4; n4 = 65520; break;    // dist_emb
  }
  int i = blockIdx.x * 256 + threadIdx.x;
  const int stride = gridDim.x * 256;
  for (; i < n4; i += stride) {
    const float4 v = reinterpret_cast<const float4*>(s)[i];
    uint2 o;
    o.x = pk2(v.x, v.y);
    o.y = pk2(v.z, v.w);
    reinterpret_cast<uint2*>(d)[i] = o;
  }
}

// ---------------- Fused Q/K/V projection: O = bf16((X @ W^T + b) * scale) ----
// Q (wsel==0) pre-scaled by 0.125 (exact in bf16) to fold 1/sqrt(64).
__global__ __launch_bounds__(256) void proj_mfma(
    const u16* __restrict__ Xb, const u16* __restrict__ W0,
    const u16* __restrict__ W1, const u16* __restrict__ W2,
    const float* __restrict__ b0, const float* __restrict__ b1,
    const float* __restrict__ b2,
    u16* __restrict__ O0, u16* __restrict__ O1, u16* __restrict__ O2) {
  __shared__ u16 sA[128 * 64];
  __shared__ u16 sB[128 * 64];
  const int t = threadIdx.x, lane = t & 63, w = t >> 6;
  const int g = lane >> 4, li = lane & 15;
  const int wsel = blockIdx.x >> 3;
  const int n0 = (blockIdx.x & 7) * 128, m0 = blockIdx.y * 128;
  const u16* Wb = wsel == 0 ? W0 : (wsel == 1 ? W1 : W2);
  const float* bias = wsel == 0 ? b0 : (wsel == 1 ? b1 : b2);
  u16* Ob = wsel == 0 ? O0 : (wsel == 1 ? O1 : O2);
  const float oscale = wsel == 0 ? 0.125f : 1.0f;
  const int wr = w >> 1, wc = w & 1;

  f32x4 acc[4][4];
#pragma unroll
  for (int i = 0; i < 4; ++i)
#pragma unroll
    for (int j = 0; j < 4; ++j) acc[i][j] = (f32x4)0.0f;

  for (int k0 = 0; k0 < HID; k0 += 64) {
    __syncthreads();
#pragma unroll
    for (int i = 0; i < 4; ++i) {
      const int idx = (w * 4 + i) * 64 + lane;
      const int row = idx >> 3, sch = (idx & 7) ^ (row & 7);
      async_copy16(&sA[(w * 4 + i) * 512], Xb + (size_t)(m0 + row) * HID + k0 + sch * 8);
      async_copy16(&sB[(w * 4 + i) * 512], Wb + (size_t)(n0 + row) * HID + k0 + sch * 8);
    }
    __syncthreads();
    bf16x8 af[4][2], bfr[4][2];
#pragma unroll
    for (int i = 0; i < 4; ++i)
#pragma unroll
      for (int c = 0; c < 2; ++c)
        af[i][c] = *reinterpret_cast<const bf16x8*>(&sA[SWZ(wr * 64 + 16 * i + li, 32 * c + 8 * g)]);
#pragma unroll
    for (int j = 0; j < 4; ++j)
#pragma unroll
      for (int c = 0; c < 2; ++c)
        bfr[j][c] = *reinterpret_cast<const bf16x8*>(&sB[SWZ(wc * 64 + 16 * j + li, 32 * c + 8 * g)]);
#pragma unroll
    for (int i = 0; i < 4; ++i)
#pragma unroll
      for (int j = 0; j < 4; ++j)
#pragma unroll
        for (int c = 0; c < 2; ++c)
          acc[i][j] = __builtin_amdgcn_mfma_f32_16x16x32_bf16(af[i][c], bfr[j][c], acc[i][j], 0, 0, 0);
  }

#pragma unroll
  for (int j = 0; j < 4; ++j) {
    const float bj = bias[n0 + wc * 64 + 16 * j + li];
#pragma unroll
    for (int i = 0; i < 4; ++i)
#pragma unroll
      for (int r = 0; r < 4; ++r)
        Ob[(size_t)(m0 + wr * 64 + 16 * i + 4 * g + r) * HID + n0 + wc * 64 + 16 * j + li] =
            f2bf_hw((acc[i][j][r] + bj) * oscale);
  }
}

// ---------------- V transpose: Vt[b][h][d][s] <- V[b][s][h*64+d] ----------------
__global__ __launch_bounds__(256) void transpose_v(
    const u16* __restrict__ Vin, u16* __restrict__ Vt) {
  __shared__ u16 tile[64 * 65];
  const int t = threadIdx.x;
  const int s0 = blockIdx.x * 64, h = blockIdx.y, b = blockIdx.z;
  const int r = t >> 2, c0 = (t & 3) * 16;
  const u16* gp = Vin + (size_t)(b * SEQ + s0 + r) * HID + h * HD + c0;
  const u16x8 a0 = *reinterpret_cast<const u16x8*>(gp);
  const u16x8 a1 = *reinterpret_cast<const u16x8*>(gp + 8);
#pragma unroll
  for (int i = 0; i < 8; ++i) { tile[r * 65 + c0 + i] = a0[i]; tile[r * 65 + c0 + 8 + i] = a1[i]; }
  __syncthreads();
  const int d = t >> 2, sc = (t & 3) * 16;
  u16x8 o0, o1;
#pragma unroll
  for (int i = 0; i < 8; ++i) {
    o0[i] = tile[(sc + i) * 65 + d];
    o1[i] = tile[(sc + 8 + i) * 65 + d];
  }
  u16* op = Vt + ((size_t)(b * NH + h) * HD + d) * SEQ + s0 + sc;
  *reinterpret_cast<u16x8*>(op) = o0;
  *reinterpret_cast<u16x8*>(op + 8) = o1;
}

// ---------------- Fused MFMA attention v9 ----------------
// R8 skeleton + R8 score math (__expf; exp2f regressed in R12 — non-fast-math
// fixup code) + accX ones-MFMA denominator + ST_R=76 (even-bank-complete relq
// gather, was ~4-way at 68).
__global__ __launch_bounds__(256, 2) void attn_mfma9(
    const u16* __restrict__ Q, const u16* __restrict__ K,
    const u16* __restrict__ Vt, const u16* __restrict__ E,
    float* __restrict__ out) {
  __shared__ u16 sK0[64 * 64];     // K buffers; current one becomes P after #2
  __shared__ u16 sK1[64 * 64];
  __shared__ u16 sV[64 * 64];
  __shared__ u16 sE[128 * 64];
  __shared__ u16 sRq[128 * ST_R];  // [j][qi] transposed
  __shared__ u16 sRk[128 * ST_R];  // [j][ki]

  const int t = threadIdx.x;
  const int lane = t & 63, w = t >> 6;
  const int g = lane >> 4, li = lane & 15;
  const int q0 = blockIdx.x * 64;
  const int h = blockIdx.y, b = blockIdx.z;
  const size_t qkbase = (size_t)b * SEQ * HID + (size_t)h * HD;
  const size_t vtbase = (size_t)(b * NH + h) * HD * SEQ;

  bf16x8 qA[2];
#pragma unroll
  for (int c = 0; c < 2; ++c)
    qA[c] = *reinterpret_cast<const bf16x8*>(
        Q + qkbase + (size_t)(q0 + 16 * w + li) * HID + 32 * c + 8 * g);

  bf16x8 ones;
#pragma unroll
  for (int i = 0; i < 8; ++i) ones[i] = (short)0x3F80;  // bf16 1.0

  f32x4 accO[4];
  f32x4 accX = (f32x4)0.0f;   // row-sum of P (denominator) via ones-MFMA
#pragma unroll
  for (int n = 0; n < 4; ++n) accO[n] = (f32x4)0.0f;

  // k0-invariant gather/write bases; j = 63+qi-ki, biased so unrolled offsets
  // are non-negative compile-time constants.
  const int jb48 = 15 + 16 * w + 4 * g - li;             // in [0, 75]
  const u16* gqp = &sRq[jb48 * ST_R + 16 * w + 4 * g];   // + (48+r-16n)*ST_R + r
  const u16* gkp = &sRk[jb48 * ST_R + li];               // + (48+r-16n)*ST_R + 16n
  u16* rkw = &sRk[li * ST_R + 16 * w + 4 * g];           // + m*16*ST_R
  u16* rqw = &sRq[li * ST_R + 16 * w + 4 * g];

  const int sidx2 = w * 2 * 64 + lane;
  const int sidx4 = w * 4 * 64 + lane;

  // ---- prologue: stage K(0), E(0); drain ----
  {
    const int eb0 = 1984 + q0;
#pragma unroll
    for (int i = 0; i < 2; ++i) {
      const int idx = sidx2 + i * 64;
      const int row = idx >> 3, sch = (idx & 7) ^ (row & 7);
      async_copy16(&sK0[(w * 2 + i) * 512], K + qkbase + (size_t)row * HID + sch * 8);
    }
#pragma unroll
    for (int i = 0; i < 4; ++i) {
      const int idx = sidx4 + i * 64;
      const int row = idx >> 3, sch = (idx & 7) ^ (row & 7);
      const int er = min(max(eb0 + row, 0), 2 * MAXP - 2);
      async_copy16(&sE[(w * 4 + i) * 512], E + (size_t)er * HD + sch * 8);
    }
    vwait0();
  }

  for (int k0 = 0; k0 < SEQ; k0 += 64) {
    const int p = (k0 >> 6) & 1;
    u16* kcur = p ? sK1 : sK0;
    u16* knxt = p ? sK0 : sK1;

    __builtin_amdgcn_s_barrier();   // #1: K(t),E(t) visible; knxt/sV reusable
    // ---- issue V(t) staging and K(t+1) staging ----
#pragma unroll
    for (int i = 0; i < 2; ++i) {
      const int idx = sidx2 + i * 64;
      const int row = idx >> 3, sch = (idx & 7) ^ (row & 7);
      async_copy16(&sV[(w * 2 + i) * 512], Vt + vtbase + (size_t)row * SEQ + k0 + sch * 8);
      async_copy16(&knxt[(w * 2 + i) * 512], K + qkbase + (size_t)(k0 + 64 + row) * HID + sch * 8);
    }

    // ---- S = Q'.K^T ----
    bf16x8 kA[2];
#pragma unroll
    for (int c = 0; c < 2; ++c)
      kA[c] = *reinterpret_cast<const bf16x8*>(&kcur[SWZ(16 * w + li, 32 * c + 8 * g)]);
    f32x4 aqk[4];
#pragma unroll
    for (int n = 0; n < 4; ++n) {
      aqk[n] = (f32x4)0.0f;
#pragma unroll
      for (int c = 0; c < 2; ++c) {
        const bf16x8 kB = *reinterpret_cast<const bf16x8*>(&kcur[SWZ(16 * n + li, 32 * c + 8 * g)]);
        aqk[n] = __builtin_amdgcn_mfma_f32_16x16x32_bf16(qA[c], kB, aqk[n], 0, 0, 0);
      }
    }
    // ---- Rq = Q'.E^T, Rk = K.E^T; packed b64 writes, transposed [j][col] ----
    __builtin_amdgcn_s_setprio(1);
#pragma unroll
    for (int m = 0; m < 8; ++m) {
      bf16x8 eB[2];
#pragma unroll
      for (int c = 0; c < 2; ++c)
        eB[c] = *reinterpret_cast<const bf16x8*>(&sE[SWZ(16 * m + li, 32 * c + 8 * g)]);
      f32x4 ak = (f32x4)0.0f, aq = (f32x4)0.0f;
#pragma unroll
      for (int c = 0; c < 2; ++c) {
        ak = __builtin_amdgcn_mfma_f32_16x16x32_bf16(kA[c], eB[c], ak, 0, 0, 0);
        aq = __builtin_amdgcn_mfma_f32_16x16x32_bf16(qA[c], eB[c], aq, 0, 0, 0);
      }
      uint2 dk, dq;
      dk.x = pk2(ak[0], ak[1]); dk.y = pk2(ak[2], ak[3]);
      dq.x = pk2(aq[0], aq[1]); dq.y = pk2(aq[2], aq[3]);
      *reinterpret_cast<uint2*>(rkw + m * 16 * ST_R) = dk;
      *reinterpret_cast<uint2*>(rqw + m * 16 * ST_R) = dq;
    }
    __builtin_amdgcn_s_setprio(0);

    vwait0();                       // V(t), K(t+1) landed (in flight since top)
    lwait0();                       // R-writes retired
    __builtin_amdgcn_s_barrier();   // #2: sRk/sRq + sV + K(t+1) visible to all

    // ---- issue E(t+1) (all sE reads happened before #2) ----
    {
      const int ebn = 1920 + q0 - k0;  // eb(t+1)
#pragma unroll
      for (int i = 0; i < 4; ++i) {
        const int idx = sidx4 + i * 64;
        const int row = idx >> 3, sch = (idx & 7) ^ (row & 7);
        const int er = min(max(ebn + row, 0), 2 * MAXP - 2);
        async_copy16(&sE[(w * 4 + i) * 512], E + (size_t)er * HD + sch * 8);
      }
    }

    // ---- scores: gather + __expf + P write (into kcur, dead K tile) ----
#pragma unroll
    for (int n = 0; n < 4; ++n)
#pragma unroll
      for (int r = 0; r < 4; ++r) {
        const float relq = bf2f(gqp[(48 + r - 16 * n) * ST_R + r]);
        const float relk = bf2f(gkp[(48 + r - 16 * n) * ST_R + 16 * n]);
        const float pr = __expf(fmaf(relk, 0.125f, aqk[n][r] + relq));
        kcur[SWZ(16 * w + 4 * g + r, 16 * n + li)] = f2bf_hw(pr);
      }

    // ---- O += P.V ; accX += P.1 (row-sum on matrix pipe) ----
    bf16x8 pA[2];
#pragma unroll
    for (int c = 0; c < 2; ++c)
      pA[c] = *reinterpret_cast<const bf16x8*>(&kcur[SWZ(16 * w + li, 32 * c + 8 * g)]);
#pragma unroll
    for (int n = 0; n < 4; ++n)
#pragma unroll
      for (int c = 0; c < 2; ++c) {
        const bf16x8 vB = *reinterpret_cast<const bf16x8*>(&sV[SWZ(16 * n + li, 32 * c + 8 * g)]);
        accO[n] = __builtin_amdgcn_mfma_f32_16x16x32_bf16(pA[c], vB, accO[n], 0, 0, 0);
      }
#pragma unroll
    for (int c = 0; c < 2; ++c)
      accX = __builtin_amdgcn_mfma_f32_16x16x32_bf16(pA[c], ones, accX, 0, 0, 0);

    vwait0();                       // E(t+1) landed (in flight since #2)
  }

  // ---- epilogue: normalize (accX holds row-sums in every lane), store ----
#pragma unroll
  for (int r = 0; r < 4; ++r) {
    const float inv = 1.0f / accX[r];
    const size_t row = (size_t)(b * SEQ + q0 + 16 * w + 4 * g + r) * HID + h * HD;
#pragma unroll
    for (int n = 0; n < 4; ++n) out[row + 16 * n + li] = accO[n][r] * inv;
  }
}

extern "C" void kernel_launch(void* const* d_in, const int* in_sizes, int n_in,
                              void* d_out, int out_size, void* d_ws, size_t ws_size,
                              hipStream_t stream) {
  const float* hs = (const float*)d_in[0];
  const float* Wq = (const float*)d_in[1];
  const float* bq = (const float*)d_in[2];
  const float* Wk = (const float*)d_in[3];
  const float* bk = (const float*)d_in[4];
  const float* Wv = (const float*)d_in[5];
  const float* bv = (const float*)d_in[6];
  const float* de = (const float*)d_in[7];
  float* out = (float*)d_out;

  // Sizes: hs = 4,194,304 floats; W* = 1,048,576; de = 262,080.
  u16* Xb  = (u16*)d_ws;                 // 4,194,304 u16
  u16* Wqb = Xb + (size_t)4194304;       // 1,048,576 each
  u16* Wkb = Wqb + (size_t)1048576;
  u16* Wvb = Wkb + (size_t)1048576;
  u16* Qb  = Wvb + (size_t)1048576;      // 4,194,304 each
  u16* Kb  = Qb + (size_t)4194304;
  u16* Vb  = Kb + (size_t)4194304;
  u16* Eb  = Vb + (size_t)4194304;       // 262,080
  u16* Vtb = Xb;                         // alias: Xb dead after proj_mfma

  dim3 blk(256);
  hipLaunchKernelGGL(cvt_multi, dim3(1024, 5), blk, 0, stream,
                     hs, Wq, Wk, Wv, de, Xb, Wqb, Wkb, Wvb, Eb);
  hipLaunchKernelGGL(proj_mfma, dim3(24, 32), blk, 0, stream,
                     Xb, Wqb, Wkb, Wvb, bq, bk, bv, Qb, Kb, Vb);
  hipLaunchKernelGGL(transpose_v, dim3(SEQ / 64, NH, 2), blk, 0, stream, Vb, Vtb);
  hipLaunchKernelGGL(attn_mfma9, dim3(SEQ / 64, NH, 2), blk, 0, stream, Qb, Kb, Vtb, Eb, out);
}

// Round 14
// 221.554 us; speedup vs baseline: 1.3765x; 1.0574x over previous
//
#include <hip/hip_runtime.h>
#include <hip/hip_bf16.h>

#define NH 16
#define HD 64
#define SEQ 2048
#define HID 1024
#define MAXP 2048
#define ST_R 76   // u16 stride of transposed R tiles; 152B rows: b64-aligned,
                  // and 6*li mod 32 covers all 16 even banks once -> 2-way reads

typedef float f32x4 __attribute__((ext_vector_type(4)));
typedef short bf16x8 __attribute__((ext_vector_type(8)));
typedef unsigned short u16;
typedef unsigned short u16x8 __attribute__((ext_vector_type(8)));

// Scalar HW convert; compiler fuses adjacent pairs into v_cvt_pk_bf16_f32 (m240).
__device__ __forceinline__ u16 f2bf_hw(float x) {
  union { __hip_bfloat16 h; u16 u; } v;
  v.h = __float2bfloat16(x);
  return v.u;
}
__device__ __forceinline__ unsigned pk2(float a, float b) {
  return (unsigned)f2bf_hw(a) | ((unsigned)f2bf_hw(b) << 16);
}
__device__ __forceinline__ float bf2f(u16 h) {
  union { unsigned u; float f; } v; v.u = ((unsigned)h) << 16;
  return v.f;
}

// XOR-swizzle for bf16 tiles with 64-elem (128B) row stride.
#define SWZ(r, c) ((r) * 64 + ((((c) >> 3) ^ ((r) & 7)) << 3) + ((c) & 7))

// async global->LDS 16B: LDS dest = wave-uniform base + lane*16; global src per-lane.
__device__ __forceinline__ void async_copy16(void* lds, const void* g) {
  __builtin_amdgcn_global_load_lds(
      (const __attribute__((address_space(1))) unsigned int*)g,
      (__attribute__((address_space(3))) unsigned int*)lds, 16, 0, 0);
}
__device__ __forceinline__ void vwait0() { asm volatile("s_waitcnt vmcnt(0)" ::: "memory"); }
__device__ __forceinline__ void lwait0() { asm volatile("s_waitcnt lgkmcnt(0)" ::: "memory"); }

// ---------------- fused fp32 -> bf16 bulk convert (5 regions, 1 launch) ----------------
__global__ __launch_bounds__(256) void cvt_multi(
    const float* __restrict__ s0, const float* __restrict__ s1,
    const float* __restrict__ s2, const float* __restrict__ s3,
    const float* __restrict__ s4,
    u16* __restrict__ d0, u16* __restrict__ d1, u16* __restrict__ d2,
    u16* __restrict__ d3, u16* __restrict__ d4) {
  const float* s; u16* d; int n4;
  switch (blockIdx.y) {
    case 0: s = s0; d = d0; n4 = 1048576; break;   // hidden_states
    case 1: s = s1; d = d1; n4 = 262144; break;    // Wq
    case 2: s = s2; d = d2; n4 = 262144; break;    // Wk
    case 3: s = s3; d = d3; n4 = 262144; break;    // Wv
    default: s = s4; d = d4; n4 = 65520; break;    // dist_emb
  }
  int i = blockIdx.x * 256 + threadIdx.x;
  const int stride = gridDim.x * 256;
  for (; i < n4; i += stride) {
    const float4 v = reinterpret_cast<const float4*>(s)[i];
    uint2 o;
    o.x = pk2(v.x, v.y);
    o.y = pk2(v.z, v.w);
    reinterpret_cast<uint2*>(d)[i] = o;
  }
}

// ---------------- Fused Q/K/V projection: O = bf16((X @ W^T + b) * scale) ----
// Q (wsel==0) pre-scaled by 0.125 (exact in bf16) to fold 1/sqrt(64).
__global__ __launch_bounds__(256) void proj_mfma(
    const u16* __restrict__ Xb, const u16* __restrict__ W0,
    const u16* __restrict__ W1, const u16* __restrict__ W2,
    const float* __restrict__ b0, const float* __restrict__ b1,
    const float* __restrict__ b2,
    u16* __restrict__ O0, u16* __restrict__ O1, u16* __restrict__ O2) {
  __shared__ u16 sA[128 * 64];
  __shared__ u16 sB[128 * 64];
  const int t = threadIdx.x, lane = t & 63, w = t >> 6;
  const int g = lane >> 4, li = lane & 15;
  const int wsel = blockIdx.x >> 3;
  const int n0 = (blockIdx.x & 7) * 128, m0 = blockIdx.y * 128;
  const u16* Wb = wsel == 0 ? W0 : (wsel == 1 ? W1 : W2);
  const float* bias = wsel == 0 ? b0 : (wsel == 1 ? b1 : b2);
  u16* Ob = wsel == 0 ? O0 : (wsel == 1 ? O1 : O2);
  const float oscale = wsel == 0 ? 0.125f : 1.0f;
  const int wr = w >> 1, wc = w & 1;

  f32x4 acc[4][4];
#pragma unroll
  for (int i = 0; i < 4; ++i)
#pragma unroll
    for (int j = 0; j < 4; ++j) acc[i][j] = (f32x4)0.0f;

  for (int k0 = 0; k0 < HID; k0 += 64) {
    __syncthreads();
#pragma unroll
    for (int i = 0; i < 4; ++i) {
      const int idx = (w * 4 + i) * 64 + lane;
      const int row = idx >> 3, sch = (idx & 7) ^ (row & 7);
      async_copy16(&sA[(w * 4 + i) * 512], Xb + (size_t)(m0 + row) * HID + k0 + sch * 8);
      async_copy16(&sB[(w * 4 + i) * 512], Wb + (size_t)(n0 + row) * HID + k0 + sch * 8);
    }
    __syncthreads();
    bf16x8 af[4][2], bfr[4][2];
#pragma unroll
    for (int i = 0; i < 4; ++i)
#pragma unroll
      for (int c = 0; c < 2; ++c)
        af[i][c] = *reinterpret_cast<const bf16x8*>(&sA[SWZ(wr * 64 + 16 * i + li, 32 * c + 8 * g)]);
#pragma unroll
    for (int j = 0; j < 4; ++j)
#pragma unroll
      for (int c = 0; c < 2; ++c)
        bfr[j][c] = *reinterpret_cast<const bf16x8*>(&sB[SWZ(wc * 64 + 16 * j + li, 32 * c + 8 * g)]);
#pragma unroll
    for (int i = 0; i < 4; ++i)
#pragma unroll
      for (int j = 0; j < 4; ++j)
#pragma unroll
        for (int c = 0; c < 2; ++c)
          acc[i][j] = __builtin_amdgcn_mfma_f32_16x16x32_bf16(af[i][c], bfr[j][c], acc[i][j], 0, 0, 0);
  }

#pragma unroll
  for (int j = 0; j < 4; ++j) {
    const float bj = bias[n0 + wc * 64 + 16 * j + li];
#pragma unroll
    for (int i = 0; i < 4; ++i)
#pragma unroll
      for (int r = 0; r < 4; ++r)
        Ob[(size_t)(m0 + wr * 64 + 16 * i + 4 * g + r) * HID + n0 + wc * 64 + 16 * j + li] =
            f2bf_hw((acc[i][j][r] + bj) * oscale);
  }
}

// ---------------- V transpose: Vt[b][h][d][s] <- V[b][s][h*64+d] ----------------
__global__ __launch_bounds__(256) void transpose_v(
    const u16* __restrict__ Vin, u16* __restrict__ Vt) {
  __shared__ u16 tile[64 * 65];
  const int t = threadIdx.x;
  const int s0 = blockIdx.x * 64, h = blockIdx.y, b = blockIdx.z;
  const int r = t >> 2, c0 = (t & 3) * 16;
  const u16* gp = Vin + (size_t)(b * SEQ + s0 + r) * HID + h * HD + c0;
  const u16x8 a0 = *reinterpret_cast<const u16x8*>(gp);
  const u16x8 a1 = *reinterpret_cast<const u16x8*>(gp + 8);
#pragma unroll
  for (int i = 0; i < 8; ++i) { tile[r * 65 + c0 + i] = a0[i]; tile[r * 65 + c0 + 8 + i] = a1[i]; }
  __syncthreads();
  const int d = t >> 2, sc = (t & 3) * 16;
  u16x8 o0, o1;
#pragma unroll
  for (int i = 0; i < 8; ++i) {
    o0[i] = tile[(sc + i) * 65 + d];
    o1[i] = tile[(sc + 8 + i) * 65 + d];
  }
  u16* op = Vt + ((size_t)(b * NH + h) * HD + d) * SEQ + s0 + sc;
  *reinterpret_cast<u16x8*>(op) = o0;
  *reinterpret_cast<u16x8*>(op + 8) = o1;
}

// ---------------- Fused MFMA attention v10: band-restricted R phase ----------------
// R13 + Toeplitz band restriction: only the consumed diagonal band of the
// Rq/Rk rectangles is computed. Wave w's relq gather touches j-groups w..w+4
// only; its Rk columns are gathered at j-groups 3-w..7-w only (verified
// against the cross-wave gather index algebra). R-phase: 32->20 MFMA,
// 32->20 pk2, 16->10 b64 writes per wave/iter. Skipped rows are never read.
__global__ __launch_bounds__(256, 2) void attn_mfma10(
    const u16* __restrict__ Q, const u16* __restrict__ K,
    const u16* __restrict__ Vt, const u16* __restrict__ E,
    float* __restrict__ out) {
  __shared__ u16 sK0[64 * 64];     // K buffers; current one becomes P after #2
  __shared__ u16 sK1[64 * 64];
  __shared__ u16 sV[64 * 64];
  __shared__ u16 sE[128 * 64];
  __shared__ u16 sRq[128 * ST_R];  // [j][qi] transposed
  __shared__ u16 sRk[128 * ST_R];  // [j][ki]

  const int t = threadIdx.x;
  const int lane = t & 63, w = t >> 6;
  const int g = lane >> 4, li = lane & 15;
  const int q0 = blockIdx.x * 64;
  const int h = blockIdx.y, b = blockIdx.z;
  const size_t qkbase = (size_t)b * SEQ * HID + (size_t)h * HD;
  const size_t vtbase = (size_t)(b * NH + h) * HD * SEQ;

  bf16x8 qA[2];
#pragma unroll
  for (int c = 0; c < 2; ++c)
    qA[c] = *reinterpret_cast<const bf16x8*>(
        Q + qkbase + (size_t)(q0 + 16 * w + li) * HID + 32 * c + 8 * g);

  bf16x8 ones;
#pragma unroll
  for (int i = 0; i < 8; ++i) ones[i] = (short)0x3F80;  // bf16 1.0

  f32x4 accO[4];
  f32x4 accX = (f32x4)0.0f;   // row-sum of P (denominator) via ones-MFMA
#pragma unroll
  for (int n = 0; n < 4; ++n) accO[n] = (f32x4)0.0f;

  // k0-invariant gather/write bases; j = 63+qi-ki, biased so unrolled offsets
  // are non-negative compile-time constants.
  const int jb48 = 15 + 16 * w + 4 * g - li;             // in [0, 75]
  const u16* gqp = &sRq[jb48 * ST_R + 16 * w + 4 * g];   // + (48+r-16n)*ST_R + r
  const u16* gkp = &sRk[jb48 * ST_R + li];               // + (48+r-16n)*ST_R + 16n
  // Band-restricted R write bases (k0-invariant): Rq groups m=w+mm, Rk m=(3-w)+mm.
  u16* rqw = &sRq[(16 * w + li) * ST_R + 16 * w + 4 * g];          // + mm*16*ST_R
  u16* rkw = &sRk[(16 * (3 - w) + li) * ST_R + 16 * w + 4 * g];    // + mm*16*ST_R
  // Matching E fragment bases (rows 16*(w+mm)+li and 16*(3-w+mm)+li).
  const u16* eqb[2];
  const u16* ekb[2];
#pragma unroll
  for (int c = 0; c < 2; ++c) {
    eqb[c] = &sE[SWZ(16 * w + li, 32 * c + 8 * g)];                // + mm*1024
    ekb[c] = &sE[SWZ(16 * (3 - w) + li, 32 * c + 8 * g)];          // + mm*1024
  }

  const int sidx2 = w * 2 * 64 + lane;
  const int sidx4 = w * 4 * 64 + lane;

  // ---- prologue: stage K(0), E(0); drain ----
  {
    const int eb0 = 1984 + q0;
#pragma unroll
    for (int i = 0; i < 2; ++i) {
      const int idx = sidx2 + i * 64;
      const int row = idx >> 3, sch = (idx & 7) ^ (row & 7);
      async_copy16(&sK0[(w * 2 + i) * 512], K + qkbase + (size_t)row * HID + sch * 8);
    }
#pragma unroll
    for (int i = 0; i < 4; ++i) {
      const int idx = sidx4 + i * 64;
      const int row = idx >> 3, sch = (idx & 7) ^ (row & 7);
      const int er = min(max(eb0 + row, 0), 2 * MAXP - 2);
      async_copy16(&sE[(w * 4 + i) * 512], E + (size_t)er * HD + sch * 8);
    }
    vwait0();
  }

  for (int k0 = 0; k0 < SEQ; k0 += 64) {
    const int p = (k0 >> 6) & 1;
    u16* kcur = p ? sK1 : sK0;
    u16* knxt = p ? sK0 : sK1;

    __builtin_amdgcn_s_barrier();   // #1: K(t),E(t) visible; knxt/sV reusable
    // ---- issue V(t) staging and K(t+1) staging ----
#pragma unroll
    for (int i = 0; i < 2; ++i) {
      const int idx = sidx2 + i * 64;
      const int row = idx >> 3, sch = (idx & 7) ^ (row & 7);
      async_copy16(&sV[(w * 2 + i) * 512], Vt + vtbase + (size_t)row * SEQ + k0 + sch * 8);
      async_copy16(&knxt[(w * 2 + i) * 512], K + qkbase + (size_t)(k0 + 64 + row) * HID + sch * 8);
    }

    // ---- S = Q'.K^T ----
    bf16x8 kA[2];
#pragma unroll
    for (int c = 0; c < 2; ++c)
      kA[c] = *reinterpret_cast<const bf16x8*>(&kcur[SWZ(16 * w + li, 32 * c + 8 * g)]);
    f32x4 aqk[4];
#pragma unroll
    for (int n = 0; n < 4; ++n) {
      aqk[n] = (f32x4)0.0f;
#pragma unroll
      for (int c = 0; c < 2; ++c) {
        const bf16x8 kB = *reinterpret_cast<const bf16x8*>(&kcur[SWZ(16 * n + li, 32 * c + 8 * g)]);
        aqk[n] = __builtin_amdgcn_mfma_f32_16x16x32_bf16(qA[c], kB, aqk[n], 0, 0, 0);
      }
    }
    // ---- band-restricted R: Rq groups w..w+4, Rk groups 3-w..7-w ----
    __builtin_amdgcn_s_setprio(1);
#pragma unroll
    for (int mm = 0; mm < 5; ++mm) {
      bf16x8 eq[2], ek[2];
#pragma unroll
      for (int c = 0; c < 2; ++c) {
        eq[c] = *reinterpret_cast<const bf16x8*>(eqb[c] + mm * 1024);
        ek[c] = *reinterpret_cast<const bf16x8*>(ekb[c] + mm * 1024);
      }
      f32x4 aq = (f32x4)0.0f, ak = (f32x4)0.0f;
#pragma unroll
      for (int c = 0; c < 2; ++c) {
        aq = __builtin_amdgcn_mfma_f32_16x16x32_bf16(qA[c], eq[c], aq, 0, 0, 0);
        ak = __builtin_amdgcn_mfma_f32_16x16x32_bf16(kA[c], ek[c], ak, 0, 0, 0);
      }
      uint2 dq, dk;
      dq.x = pk2(aq[0], aq[1]); dq.y = pk2(aq[2], aq[3]);
      dk.x = pk2(ak[0], ak[1]); dk.y = pk2(ak[2], ak[3]);
      *reinterpret_cast<uint2*>(rqw + mm * 16 * ST_R) = dq;
      *reinterpret_cast<uint2*>(rkw + mm * 16 * ST_R) = dk;
    }
    __builtin_amdgcn_s_setprio(0);

    vwait0();                       // V(t), K(t+1) landed (in flight since top)
    lwait0();                       // R-writes retired
    __builtin_amdgcn_s_barrier();   // #2: sRk/sRq + sV + K(t+1) visible to all

    // ---- issue E(t+1) (all sE reads happened before #2) ----
    {
      const int ebn = 1920 + q0 - k0;  // eb(t+1)
#pragma unroll
      for (int i = 0; i < 4; ++i) {
        const int idx = sidx4 + i * 64;
        const int row = idx >> 3, sch = (idx & 7) ^ (row & 7);
        const int er = min(max(ebn + row, 0), 2 * MAXP - 2);
        async_copy16(&sE[(w * 4 + i) * 512], E + (size_t)er * HD + sch * 8);
      }
    }

    // ---- scores: gather + __expf + P write (into kcur, dead K tile) ----
#pragma unroll
    for (int n = 0; n < 4; ++n)
#pragma unroll
      for (int r = 0; r < 4; ++r) {
        const float relq = bf2f(gqp[(48 + r - 16 * n) * ST_R + r]);
        const float relk = bf2f(gkp[(48 + r - 16 * n) * ST_R + 16 * n]);
        const float pr = __expf(fmaf(relk, 0.125f, aqk[n][r] + relq));
        kcur[SWZ(16 * w + 4 * g + r, 16 * n + li)] = f2bf_hw(pr);
      }

    // ---- O += P.V ; accX += P.1 (row-sum on matrix pipe) ----
    bf16x8 pA[2];
#pragma unroll
    for (int c = 0; c < 2; ++c)
      pA[c] = *reinterpret_cast<const bf16x8*>(&kcur[SWZ(16 * w + li, 32 * c + 8 * g)]);
#pragma unroll
    for (int n = 0; n < 4; ++n)
#pragma unroll
      for (int c = 0; c < 2; ++c) {
        const bf16x8 vB = *reinterpret_cast<const bf16x8*>(&sV[SWZ(16 * n + li, 32 * c + 8 * g)]);
        accO[n] = __builtin_amdgcn_mfma_f32_16x16x32_bf16(pA[c], vB, accO[n], 0, 0, 0);
      }
#pragma unroll
    for (int c = 0; c < 2; ++c)
      accX = __builtin_amdgcn_mfma_f32_16x16x32_bf16(pA[c], ones, accX, 0, 0, 0);

    vwait0();                       // E(t+1) landed (in flight since #2)
  }

  // ---- epilogue: normalize (accX holds row-sums in every lane), store ----
#pragma unroll
  for (int r = 0; r < 4; ++r) {
    const float inv = 1.0f / accX[r];
    const size_t row = (size_t)(b * SEQ + q0 + 16 * w + 4 * g + r) * HID + h * HD;
#pragma unroll
    for (int n = 0; n < 4; ++n) out[row + 16 * n + li] = accO[n][r] * inv;
  }
}

extern "C" void kernel_launch(void* const* d_in, const int* in_sizes, int n_in,
                              void* d_out, int out_size, void* d_ws, size_t ws_size,
                              hipStream_t stream) {
  const float* hs = (const float*)d_in[0];
  const float* Wq = (const float*)d_in[1];
  const float* bq = (const float*)d_in[2];
  const float* Wk = (const float*)d_in[3];
  const float* bk = (const float*)d_in[4];
  const float* Wv = (const float*)d_in[5];
  const float* bv = (const float*)d_in[6];
  const float* de = (const float*)d_in[7];
  float* out = (float*)d_out;

  // Sizes: hs = 4,194,304 floats; W* = 1,048,576; de = 262,080.
  u16* Xb  = (u16*)d_ws;                 // 4,194,304 u16
  u16* Wqb = Xb + (size_t)4194304;       // 1,048,576 each
  u16* Wkb = Wqb + (size_t)1048576;
  u16* Wvb = Wkb + (size_t)1048576;
  u16* Qb  = Wvb + (size_t)1048576;      // 4,194,304 each
  u16* Kb  = Qb + (size_t)4194304;
  u16* Vb  = Kb + (size_t)4194304;
  u16* Eb  = Vb + (size_t)4194304;       // 262,080
  u16* Vtb = Xb;                         // alias: Xb dead after proj_mfma

  dim3 blk(256);
  hipLaunchKernelGGL(cvt_multi, dim3(1024, 5), blk, 0, stream,
                     hs, Wq, Wk, Wv, de, Xb, Wqb, Wkb, Wvb, Eb);
  hipLaunchKernelGGL(proj_mfma, dim3(24, 32), blk, 0, stream,
                     Xb, Wqb, Wkb, Wvb, bq, bk, bv, Qb, Kb, Vb);
  hipLaunchKernelGGL(transpose_v, dim3(SEQ / 64, NH, 2), blk, 0, stream, Vb, Vtb);
  hipLaunchKernelGGL(attn_mfma10, dim3(SEQ / 64, NH, 2), blk, 0, stream, Qb, Kb, Vtb, Eb, out);
}